// Round 12
// baseline (84.700 us; speedup 1.0000x reference)
//
#include <hip/hip_runtime.h>
#include <math.h>

#define SRATE   32000
#define NFFT    1024
#define HOP     320
#define NBINS   513
#define NMELS   128
#define NFRAMES 1001
#define NB      16
#define TLEN    320000
#define PCEN_EPS 1e-6f
#define LN_EPS   1e-6f
#define MAXW     64   // max nonzero band width per mel column (measured ~27)

// ---- parallel-scan decomposition of the PCEN EMA ----
#define CL      16                    // chunk length (timesteps)
#define NCHUNK  63                    // ceil(1001/16)

// LDS pad for interleaved-complex float2 arrays: 1 extra complex per 8.
__device__ __forceinline__ int P(int i) { return i + (i >> 3); }
#define ZPAD 1152   // P(1023) = 1150

// base-4 digit reverse of a 10-bit index (5 digits)
__device__ __forceinline__ int DR4(int e) {
    return ((e & 3) << 8) | (((e >> 2) & 3) << 6) | (((e >> 4) & 3) << 4)
         | (((e >> 6) & 3) << 2) | ((e >> 8) & 3);
}

// ---------------------------------------------------------------------------
// Parallel prep: one block per mel packs the filterbank band; 5 extra blocks
// build the window and float2 twiddle tables.
__global__ __launch_bounds__(256) void k_prep(
    const float* __restrict__ fb, int* __restrict__ kmin, int* __restrict__ klen,
    float* __restrict__ wv, float* __restrict__ win, float2* __restrict__ twg)
{
    const int blk = blockIdx.x;
    const int tid = threadIdx.x;
    if (blk < NMELS) {
        const int m = blk;
        __shared__ int smin[4], smax[4];
        int lmin = 1 << 30, lmax = -1;
        for (int k = tid; k < NBINS; k += 256) {
            if (fb[k * NMELS + m] > 0.f) {
                if (k < lmin) lmin = k;
                if (k > lmax) lmax = k;
            }
        }
        #pragma unroll
        for (int off = 32; off; off >>= 1) {
            int om = __shfl_xor(lmin, off); if (om < lmin) lmin = om;
            int ox = __shfl_xor(lmax, off); if (ox > lmax) lmax = ox;
        }
        if ((tid & 63) == 0) { smin[tid >> 6] = lmin; smax[tid >> 6] = lmax; }
        __syncthreads();
        int k0 = min(min(smin[0], smin[1]), min(smin[2], smin[3]));
        int k1 = max(max(smax[0], smax[1]), max(smax[2], smax[3]));
        int L  = (k1 < 0) ? 0 : min(k1 - k0 + 1, MAXW);
        if (tid == 0) { kmin[m] = (k1 < 0) ? 0 : k0; klen[m] = L; }
        if (tid < L) wv[m * MAXW + tid] = fb[(k0 + tid) * NMELS + m];
    } else {
        const int i = (blk - NMELS) * 256 + tid;   // 0..1279
        if (i < NFFT) {
            float sp = sinpif((float)i * (1.0f / (float)NFFT));
            win[i] = sp * sp;
        } else if (i < NFFT + 256) {
            int n = i - NFFT;
            float sn, cn;
            sincospif((float)n * (1.0f / 512.0f), &sn, &cn);
            twg[n] = make_float2(cn, -sn);
        }
    }
}

// ---------------------------------------------------------------------------
// One block = FOUR frames = TWO two-for-one real FFTs. IN-PLACE radix-4 DIF
// (single z buffer, digit-reversed output resolved via prt[] table). 22.5 KB
// LDS -> 7 blocks/CU (vs 4 for the ping-pong version): latency hiding.
__global__ __launch_bounds__(256, 7) void k_melspec(
    const float* __restrict__ x,
    const int*   __restrict__ kmin,
    const int*   __restrict__ klen,
    const float* __restrict__ wv,
    const float* __restrict__ fb,     // dense fallback
    const float* __restrict__ win_g,
    const float2* __restrict__ twg,
    float* __restrict__ E,
    int usePacked)
{
    __shared__ float2 z[2][ZPAD];          // 18,432 B
    __shared__ float2 tws[256];            //  2,048 B
    __shared__ unsigned short prt[1024];   //  2,048 B  (slot of X[k])

    const int tid = threadIdx.x;
    const int g   = blockIdx.x;          // frames 4g .. 4g+3

    if (usePacked) {
        tws[tid] = twg[tid];
    } else {
        float sn, cn;
        sincospif((float)tid * (1.0f / 512.0f), &sn, &cn);
        tws[tid] = make_float2(cn, -sn);
    }
    #pragma unroll
    for (int e = tid; e < 1024; e += 256)
        prt[e] = (unsigned short)P(DR4(e));

    // ---- load 4 frames (2 per FFT: re=even frame, im=odd frame) ----
    const int i0 = tid * 4;
    #pragma unroll
    for (int u = 0; u < 2; ++u) {
        const int fa = 4 * g + 2 * u;
        const int fbr = fa + 1;
        const int ba = fa / NFRAMES,  ta = fa  - ba * NFRAMES;
        const int bb = fbr / NFRAMES, tb = fbr - bb * NFRAMES;
        const float* xa = x + (size_t)ba * TLEN;
        const float* xb = x + (size_t)bb * TLEN;
        const int basea = ta * HOP - (NFFT / 2);
        const int baseb = tb * HOP - (NFFT / 2);
        const bool safe = usePacked &&
                          basea >= 0 && baseb >= 0 &&
                          (basea + NFFT - 1 < TLEN) && (baseb + NFFT - 1 < TLEN);
        if (safe) {
            float4 v0 = *(const float4*)(xa + basea + i0);
            float4 v1 = *(const float4*)(xb + baseb + i0);
            float4 w  = *(const float4*)(win_g + i0);
            z[u][P(i0 + 0)] = make_float2(v0.x * w.x, v1.x * w.x);
            z[u][P(i0 + 1)] = make_float2(v0.y * w.y, v1.y * w.y);
            z[u][P(i0 + 2)] = make_float2(v0.z * w.z, v1.z * w.z);
            z[u][P(i0 + 3)] = make_float2(v0.w * w.w, v1.w * w.w);
        } else {
            #pragma unroll
            for (int q = 0; q < 4; ++q) {
                const int i = i0 + q;
                int j0 = basea + i;
                j0 = (j0 < 0) ? -j0 : ((j0 >= TLEN) ? (2 * TLEN - 2 - j0) : j0);
                int j1 = baseb + i;
                j1 = (j1 < 0) ? -j1 : ((j1 >= TLEN) ? (2 * TLEN - 2 - j1) : j1);
                float w;
                if (usePacked) w = win_g[i];
                else { float sp = sinpif((float)i * (1.0f / (float)NFFT)); w = sp * sp; }
                z[u][P(i)] = make_float2(xa[j0] * w, xb[j1] * w);
            }
        }
    }
    __syncthreads();

    // ---- in-place radix-4 DIF, stages 0..3 (twiddled) ----
    #pragma unroll
    for (int s = 0; s < 4; ++s) {
        const int q    = 256 >> (2 * s);
        const int k    = tid & (q - 1);
        const int base = ((tid & ~(q - 1)) << 2) | k;   // j*4q + k
        const int n    = k << (2 * s);
        float2 w1 = tws[n];
        const float c1 = w1.x, s1 = w1.y;
        const float c2 = c1 * c1 - s1 * s1, s2 = 2.f * c1 * s1;
        const float c3 = c1 * c2 - s1 * s2, s3 = c1 * s2 + s1 * c2;
        #pragma unroll
        for (int u = 0; u < 2; ++u) {
            float2 a0 = z[u][P(base)];
            float2 a1 = z[u][P(base + q)];
            float2 a2 = z[u][P(base + 2 * q)];
            float2 a3 = z[u][P(base + 3 * q)];
            float t0r = a0.x + a2.x, t0i = a0.y + a2.y;
            float t1r = a0.x - a2.x, t1i = a0.y - a2.y;
            float t2r = a1.x + a3.x, t2i = a1.y + a3.y;
            float t3r = a1.y - a3.y, t3i = a3.x - a1.x;   // -i*(a1-a3)
            float y1r = t1r + t3r, y1i = t1i + t3i;
            float y2r = t0r - t2r, y2i = t0i - t2i;
            float y3r = t1r - t3r, y3i = t1i - t3i;
            z[u][P(base)]         = make_float2(t0r + t2r,           t0i + t2i);
            z[u][P(base + q)]     = make_float2(y1r * c1 - y1i * s1, y1r * s1 + y1i * c1);
            z[u][P(base + 2 * q)] = make_float2(y2r * c2 - y2i * s2, y2r * s2 + y2i * c2);
            z[u][P(base + 3 * q)] = make_float2(y3r * c3 - y3i * s3, y3r * s3 + y3i * c3);
        }
        __syncthreads();
    }

    // ---- stage 4 (q=1): twiddles are all 1 ----
    {
        const int base = tid << 2;
        #pragma unroll
        for (int u = 0; u < 2; ++u) {
            float2 a0 = z[u][P(base)];
            float2 a1 = z[u][P(base + 1)];
            float2 a2 = z[u][P(base + 2)];
            float2 a3 = z[u][P(base + 3)];
            float t0r = a0.x + a2.x, t0i = a0.y + a2.y;
            float t1r = a0.x - a2.x, t1i = a0.y - a2.y;
            float t2r = a1.x + a3.x, t2i = a1.y + a3.y;
            float t3r = a1.y - a3.y, t3i = a3.x - a1.x;
            z[u][P(base)]     = make_float2(t0r + t2r, t0i + t2i);
            z[u][P(base + 1)] = make_float2(t1r + t3r, t1i + t3i);
            z[u][P(base + 2)] = make_float2(t0r - t2r, t0i - t2i);
            z[u][P(base + 3)] = make_float2(t1r - t3r, t1i - t3i);
        }
        __syncthreads();
    }

    // ---- untangle (in place, no cross-thread hazard): each 128-thread half
    //      handles its FFT; bin k's power pair overwrites slot prt[k] ----
    {
        const int u  = tid >> 7;
        const int kk = tid & 127;
        for (int k = kk; k < 513; k += 128) {
            const int sk  = prt[k];
            const int skr = prt[(NFFT - k) & (NFFT - 1)];
            float2 Z  = z[u][sk];
            float2 Zr = z[u][skr];
            float x1r = Z.x + Zr.x, x1i = Z.y - Zr.y;
            float x2r = Z.y + Zr.y, x2i = Zr.x - Z.x;
            z[u][sk] = make_float2(0.25f * (x1r * x1r + x1i * x1i),
                                   0.25f * (x2r * x2r + x2i * x2i));
        }
    }
    __syncthreads();

    // ---- mel projection: half u, mel m; both frames of FFT u at once ----
    {
        const int u = tid >> 7;
        const int m = tid & 127;
        const int fa = 4 * g + 2 * u;
        float acc0 = 0.f, acc1 = 0.f;
        if (usePacked) {
            const int k0 = kmin[m], L = klen[m];
            const float* w = wv + m * MAXW;
            for (int j = 0; j < L; ++j) {
                float2 pk = z[u][prt[k0 + j]];
                float ww = w[j];
                acc0 += pk.x * ww; acc1 += pk.y * ww;
            }
        } else {
            for (int k = 0; k < NBINS; ++k) {
                float2 pk = z[u][prt[k]];
                float ww = fb[k * NMELS + m];
                acc0 += pk.x * ww; acc1 += pk.y * ww;
            }
        }
        E[(size_t)fa * NMELS + m]       = acc0;
        E[(size_t)(fa + 1) * NMELS + m] = acc1;
    }
}

// ---------------------------------------------------------------------------
// PCEN phase 1: per-(b,chunk,m) affine offset B_c = s * sum_j a^{L-1-j} e_j.
// Full chunks: 16 independent loads in flight, 4 short FMA chains merged with
// a^4/a^8/a^12. Also snapshots E[:,0,:].
__global__ __launch_bounds__(256) void k_pcen_chunk(
    const float* __restrict__ E, float* __restrict__ Bws,
    float* __restrict__ E0ws, const float* __restrict__ p_ls)
{
    const int gid = blockIdx.x * blockDim.x + threadIdx.x;
    const int m = gid & (NMELS - 1);
    const int c = (gid >> 7) % NCHUNK;
    const int b = gid / (NMELS * NCHUNK);

    const float s = expf(p_ls[0]);
    const float a = 1.f - s;

    const int t0 = c * CL;
    const int L  = (t0 + CL <= NFRAMES) ? CL : (NFRAMES - t0);
    const float* col = E + (size_t)b * NFRAMES * NMELS + m;

    if (c == 0) E0ws[b * NMELS + m] = col[0];

    float Bacc;
    if (L == CL) {
        float e[CL];
        #pragma unroll
        for (int j = 0; j < CL; ++j)
            e[j] = col[(size_t)(t0 + j) * NMELS];
        float p0 = 0.f, p1 = 0.f, p2 = 0.f, p3 = 0.f;
        #pragma unroll
        for (int u = 0; u < 4; ++u) {
            p0 = a * p0 + s * e[u];
            p1 = a * p1 + s * e[4 + u];
            p2 = a * p2 + s * e[8 + u];
            p3 = a * p3 + s * e[12 + u];
        }
        const float a2 = a * a, a4 = a2 * a2, a8 = a4 * a4, a12 = a8 * a4;
        Bacc = a12 * p0 + a8 * p1 + a4 * p2 + p3;
    } else {
        Bacc = 0.f;
        for (int j = 0; j < L; ++j)
            Bacc = a * Bacc + s * col[(size_t)(t0 + j) * NMELS];
    }
    Bws[gid] = Bacc;
}

// ---------------------------------------------------------------------------
// PCEN phase 2 fused with layernorm. One block = (b, chunk-pair). Each half
// recomputes its chunk's EMA carry by scanning Bws (batched 8-wide loads),
// replays the chunk with pointwise PCEN into LDS, then 4 waves layernorm the
// 32 frames in place.
__global__ __launch_bounds__(256) void k_pcen_ln(
    float* __restrict__ E, const float* __restrict__ Bws,
    const float* __restrict__ E0ws,
    const float* __restrict__ p_ls, const float* __restrict__ p_la,
    const float* __restrict__ p_ld, const float* __restrict__ p_lr)
{
    __shared__ float sm[2 * CL][NMELS];   // 16 KB

    const int tid  = threadIdx.x;
    const int half = tid >> 7;
    const int m    = tid & 127;
    const int b    = blockIdx.x >> 5;     // 32 chunk-pairs per batch
    const int cp   = blockIdx.x & 31;
    const int c    = cp * 2 + half;

    const float s     = expf(p_ls[0]);
    const float alpha = expf(p_la[0]);
    const float delta = expf(p_ld[0]);
    const float r     = expf(p_lr[0]);
    const float dr    = __powf(delta, r);
    const float a     = 1.f - s;
    const float a2 = a * a, a4 = a2 * a2, a8 = a4 * a4;
    const float a16 = a8 * a8;            // a^CL (all scanned chunks full)

    if (c < NCHUNK) {
        // self-scan: carry entering chunk c, 8-wide batched loads for MLP
        float M = E0ws[b * NMELS + m];
        const float* Bcol = Bws + (size_t)b * NCHUNK * NMELS + m;
        int cc = 0;
        for (; cc + 8 <= c; cc += 8) {
            float b0 = Bcol[(size_t)(cc + 0) * NMELS];
            float b1 = Bcol[(size_t)(cc + 1) * NMELS];
            float b2 = Bcol[(size_t)(cc + 2) * NMELS];
            float b3 = Bcol[(size_t)(cc + 3) * NMELS];
            float b4 = Bcol[(size_t)(cc + 4) * NMELS];
            float b5 = Bcol[(size_t)(cc + 5) * NMELS];
            float b6 = Bcol[(size_t)(cc + 6) * NMELS];
            float b7 = Bcol[(size_t)(cc + 7) * NMELS];
            M = a16 * M + b0; M = a16 * M + b1; M = a16 * M + b2; M = a16 * M + b3;
            M = a16 * M + b4; M = a16 * M + b5; M = a16 * M + b6; M = a16 * M + b7;
        }
        for (; cc < c; ++cc)
            M = a16 * M + Bcol[(size_t)cc * NMELS];

        const int t0 = c * CL;
        const int L  = (t0 + CL <= NFRAMES) ? CL : (NFRAMES - t0);
        const float* col = E + ((size_t)b * NFRAMES + t0) * NMELS + m;
        for (int j = 0; j < L; ++j) {
            float e = col[(size_t)j * NMELS];
            M = a * M + s * e;
            float den = __powf(PCEN_EPS + M, alpha);
            sm[half * CL + j][m] = __powf(e / den + delta, r) - dr;
        }
    }
    __syncthreads();

    // layernorm: 4 waves cover the 32 staged frames
    const int wid  = tid >> 6;
    const int lane = tid & 63;
    for (int row = wid; row < 2 * CL; row += 4) {
        const int cc = cp * 2 + (row >> 4);
        if (cc >= NCHUNK) continue;
        const int j   = row & (CL - 1);
        const int tt0 = cc * CL;
        const int LL  = (tt0 + CL <= NFRAMES) ? CL : (NFRAMES - tt0);
        if (j >= LL) continue;
        float v0 = sm[row][lane], v1 = sm[row][lane + 64];
        float sum = v0 + v1;
        float sq  = v0 * v0 + v1 * v1;
        #pragma unroll
        for (int off = 32; off; off >>= 1) {
            sum += __shfl_xor(sum, off);
            sq  += __shfl_xor(sq,  off);
        }
        float mu  = sum * (1.f / 128.f);
        float var = sq * (1.f / 128.f) - mu * mu;
        float inv = rsqrtf(var + LN_EPS);
        float* p = E + ((size_t)b * NFRAMES + tt0 + j) * NMELS;
        p[lane]      = (v0 - mu) * inv;
        p[lane + 64] = (v1 - mu) * inv;
    }
}

// ---------------------------------------------------------------------------
// Fallback serial PCEN + LN (used only if workspace is too small).
__global__ __launch_bounds__(256) void k_pcen_serial(
    float* __restrict__ E,
    const float* __restrict__ p_ls, const float* __restrict__ p_la,
    const float* __restrict__ p_ld, const float* __restrict__ p_lr)
{
    const int gid = blockIdx.x * blockDim.x + threadIdx.x;
    const int b = gid >> 7;
    const int m = gid & 127;

    const float s     = expf(p_ls[0]);
    const float alpha = expf(p_la[0]);
    const float delta = expf(p_ld[0]);
    const float r     = expf(p_lr[0]);
    const float dr    = powf(delta, r);
    const float a     = 1.f - s;

    float* col = E + (size_t)b * NFRAMES * NMELS + m;
    float M = col[0];
    for (int t = 0; t < NFRAMES; ++t) {
        float e = col[(size_t)t * NMELS];
        M = a * M + s * e;
        float den = __powf(PCEN_EPS + M, alpha);
        float p   = __powf(e / den + delta, r) - dr;
        col[(size_t)t * NMELS] = p;
    }
}

__global__ __launch_bounds__(256) void k_ln(float* __restrict__ out) {
    const int wid  = threadIdx.x >> 6;
    const int lane = threadIdx.x & 63;
    const int row  = blockIdx.x * 4 + wid;
    float* p = out + (size_t)row * NMELS;
    float v0 = p[lane], v1 = p[lane + 64];
    float sum = v0 + v1;
    float sq  = v0 * v0 + v1 * v1;
    #pragma unroll
    for (int off = 32; off; off >>= 1) {
        sum += __shfl_xor(sum, off);
        sq  += __shfl_xor(sq,  off);
    }
    float mu  = sum * (1.f / 128.f);
    float var = sq * (1.f / 128.f) - mu * mu;
    float inv = rsqrtf(var + LN_EPS);
    p[lane]      = (v0 - mu) * inv;
    p[lane + 64] = (v1 - mu) * inv;
}

// ---------------------------------------------------------------------------
extern "C" void kernel_launch(void* const* d_in, const int* in_sizes, int n_in,
                              void* d_out, int out_size, void* d_ws, size_t ws_size,
                              hipStream_t stream) {
    const float* x   = (const float*)d_in[0];
    const float* fb  = (const float*)d_in[1];
    const float* lsp = (const float*)d_in[2];
    const float* lap = (const float*)d_in[3];
    const float* ldp = (const float*)d_in[4];
    const float* lrp = (const float*)d_in[5];
    float* out = (float*)d_out;

    // ws layout (floats): kmin[128] klen[128] wv[8192] win[1024] tw[512]
    //                     Bws[129024] E0ws[2048]
    const size_t packElems = 128 + 128 + 8192 + 1024 + 512;
    const size_t scanElems = (size_t)NB * NCHUNK * NMELS;   // 129024
    const size_t needPack  = packElems * 4;
    const size_t needScan  = (packElems + scanElems + (size_t)NB * NMELS) * 4;

    int usePacked = (ws_size >= needPack) ? 1 : 0;
    int useScan   = (ws_size >= needScan) ? 1 : 0;

    int*    kmin = (int*)d_ws;
    int*    klen = kmin + NMELS;
    float*  wv   = (float*)(klen + NMELS);
    float*  win  = wv + (size_t)NMELS * MAXW;
    float2* twg  = (float2*)(win + NFFT);
    float*  Bws  = (float*)(twg + 256);
    float*  E0ws = Bws + scanElems;

    if (usePacked)
        k_prep<<<NMELS + 5, 256, 0, stream>>>(fb, kmin, klen, wv, win, twg);

    k_melspec<<<NB * NFRAMES / 4, 256, 0, stream>>>(
        x, kmin, klen, wv, fb, win, twg, out, usePacked);

    if (useScan) {
        const int nThread = NB * NCHUNK * NMELS;                 // 129024
        k_pcen_chunk<<<nThread / 256, 256, 0, stream>>>(out, Bws, E0ws, lsp);
        k_pcen_ln<<<NB * 32, 256, 0, stream>>>(out, Bws, E0ws, lsp, lap, ldp, lrp);
    } else {
        k_pcen_serial<<<(NB * NMELS) / 256, 256, 0, stream>>>(out, lsp, lap, ldp, lrp);
        k_ln<<<(NB * NFRAMES) / 4, 256, 0, stream>>>(out);
    }
}

// Round 13
// 78.962 us; speedup vs baseline: 1.0727x; 1.0727x over previous
//
#include <hip/hip_runtime.h>
#include <math.h>

#define SRATE   32000
#define NFFT    1024
#define HOP     320
#define NBINS   513
#define NMELS   128
#define NFRAMES 1001
#define NB      16
#define TLEN    320000
#define PCEN_EPS 1e-6f
#define LN_EPS   1e-6f
#define MAXW     64   // max nonzero band width per mel column (measured ~27)

// ---- parallel-scan decomposition of the PCEN EMA ----
#define CL      16                    // chunk length (timesteps)
#define NCHUNK  63                    // ceil(1001/16)

// Per-stage XOR swizzles for float2 LDS (bank model: conflict iff slot%16
// collides; reads are stride-256 -> free under ANY per-32-block XOR).
//   f=1: i ^ ((i>>5)&3)        -- for o=4l+p patterns (init, stage mm=1)
//   f=2: i ^ (((i>>5)&3)<<2)   -- for o=16u+v+4p pattern (stage mm=4)
//   f=0: identity              -- stages mm>=16 are naturally conflict-free
__device__ __forceinline__ int SWZ(int i, int f) {
    return f == 1 ? (i ^ ((i >> 5) & 3))
         : f == 2 ? (i ^ (((i >> 5) & 3) << 2))
         : i;
}

// ---------------------------------------------------------------------------
// Parallel prep: one block per mel packs the filterbank band; 5 extra blocks
// build the window and float2 twiddle tables.
__global__ __launch_bounds__(256) void k_prep(
    const float* __restrict__ fb, int* __restrict__ kmin, int* __restrict__ klen,
    float* __restrict__ wv, float* __restrict__ win, float2* __restrict__ twg)
{
    const int blk = blockIdx.x;
    const int tid = threadIdx.x;
    if (blk < NMELS) {
        const int m = blk;
        __shared__ int smin[4], smax[4];
        int lmin = 1 << 30, lmax = -1;
        for (int k = tid; k < NBINS; k += 256) {
            if (fb[k * NMELS + m] > 0.f) {
                if (k < lmin) lmin = k;
                if (k > lmax) lmax = k;
            }
        }
        #pragma unroll
        for (int off = 32; off; off >>= 1) {
            int om = __shfl_xor(lmin, off); if (om < lmin) lmin = om;
            int ox = __shfl_xor(lmax, off); if (ox > lmax) lmax = ox;
        }
        if ((tid & 63) == 0) { smin[tid >> 6] = lmin; smax[tid >> 6] = lmax; }
        __syncthreads();
        int k0 = min(min(smin[0], smin[1]), min(smin[2], smin[3]));
        int k1 = max(max(smax[0], smax[1]), max(smax[2], smax[3]));
        int L  = (k1 < 0) ? 0 : min(k1 - k0 + 1, MAXW);
        if (tid == 0) { kmin[m] = (k1 < 0) ? 0 : k0; klen[m] = L; }
        if (tid < L) wv[m * MAXW + tid] = fb[(k0 + tid) * NMELS + m];
    } else {
        const int i = (blk - NMELS) * 256 + tid;   // 0..1279
        if (i < NFFT) {
            float sp = sinpif((float)i * (1.0f / (float)NFFT));
            win[i] = sp * sp;
        } else if (i < NFFT + 256) {
            int n = i - NFFT;
            float sn, cn;
            sincospif((float)n * (1.0f / 512.0f), &sn, &cn);
            twg[n] = make_float2(cn, -sn);
        }
    }
}

// ---------------------------------------------------------------------------
// One block = FOUR frames = TWO two-for-one real FFTs (radix-4 Stockham,
// 5 stages, ping-pong, dense float2 buffers + per-stage XOR swizzles ->
// provably conflict-free under the b64 bank model).
__global__ __launch_bounds__(256, 4) void k_melspec(
    const float* __restrict__ x,
    const int*   __restrict__ kmin,
    const int*   __restrict__ klen,
    const float* __restrict__ wv,
    const float* __restrict__ fb,     // dense fallback
    const float* __restrict__ win_g,
    const float2* __restrict__ twg,
    float* __restrict__ E,
    int usePacked)
{
    __shared__ float2 zA[2][1024], zB[2][1024];   // 32 KB
    __shared__ float2 tws[256];                   //  2 KB

    const int tid = threadIdx.x;
    const int g   = blockIdx.x;          // frames 4g .. 4g+3

    if (usePacked) {
        tws[tid] = twg[tid];
    } else {
        float sn, cn;
        sincospif((float)tid * (1.0f / 512.0f), &sn, &cn);
        tws[tid] = make_float2(cn, -sn);
    }

    // ---- load 4 frames (2 per FFT: re=even frame, im=odd frame), swz f=1 ----
    const int i0 = tid * 4;
    #pragma unroll
    for (int u = 0; u < 2; ++u) {
        const int fa = 4 * g + 2 * u;
        const int fbr = fa + 1;
        const int ba = fa / NFRAMES,  ta = fa  - ba * NFRAMES;
        const int bb = fbr / NFRAMES, tb = fbr - bb * NFRAMES;
        const float* xa = x + (size_t)ba * TLEN;
        const float* xb = x + (size_t)bb * TLEN;
        const int basea = ta * HOP - (NFFT / 2);
        const int baseb = tb * HOP - (NFFT / 2);
        const bool safe = usePacked &&
                          basea >= 0 && baseb >= 0 &&
                          (basea + NFFT - 1 < TLEN) && (baseb + NFFT - 1 < TLEN);
        if (safe) {
            float4 v0 = *(const float4*)(xa + basea + i0);
            float4 v1 = *(const float4*)(xb + baseb + i0);
            float4 w  = *(const float4*)(win_g + i0);
            zA[u][SWZ(i0 + 0, 1)] = make_float2(v0.x * w.x, v1.x * w.x);
            zA[u][SWZ(i0 + 1, 1)] = make_float2(v0.y * w.y, v1.y * w.y);
            zA[u][SWZ(i0 + 2, 1)] = make_float2(v0.z * w.z, v1.z * w.z);
            zA[u][SWZ(i0 + 3, 1)] = make_float2(v0.w * w.w, v1.w * w.w);
        } else {
            #pragma unroll
            for (int q = 0; q < 4; ++q) {
                const int i = i0 + q;
                int j0 = basea + i;
                j0 = (j0 < 0) ? -j0 : ((j0 >= TLEN) ? (2 * TLEN - 2 - j0) : j0);
                int j1 = baseb + i;
                j1 = (j1 < 0) ? -j1 : ((j1 >= TLEN) ? (2 * TLEN - 2 - j1) : j1);
                float w;
                if (usePacked) w = win_g[i];
                else { float sp = sinpif((float)i * (1.0f / (float)NFFT)); w = sp * sp; }
                zA[u][SWZ(i, 1)] = make_float2(xa[j0] * w, xb[j1] * w);
            }
        }
    }
    __syncthreads();

    // ---- 5 radix-4 Stockham stages; read with prev stage's swizzle, write
    //      with this stage's. rf: {1,1,2,0,0}  wf: {1,2,0,0,0} ----
    float2 (*zs)[1024] = zA;
    float2 (*zd)[1024] = zB;
    #pragma unroll
    for (int st = 0; st < 5; ++st) {
        const int mm = 1 << (2 * st);
        const int n  = tid & ~(mm - 1);             // twiddle exponent j*m
        const int o  = (n << 2) | (tid & (mm - 1)); // k + 4*j*m
        const int rf = (st <= 1) ? 1 : (st == 2 ? 2 : 0);
        const int wf = (st == 0) ? 1 : (st == 1 ? 2 : 0);
        float2 w1 = tws[n];
        const float c1 = w1.x, s1 = w1.y;
        const float c2 = c1 * c1 - s1 * s1, s2 = 2.f * c1 * s1;
        const float c3 = c1 * c2 - s1 * s2, s3 = c1 * s2 + s1 * c2;
        #pragma unroll
        for (int u = 0; u < 2; ++u) {
            float2 a0 = zs[u][SWZ(tid,       rf)];
            float2 a1 = zs[u][SWZ(tid + 256, rf)];
            float2 a2 = zs[u][SWZ(tid + 512, rf)];
            float2 a3 = zs[u][SWZ(tid + 768, rf)];
            float t0r = a0.x + a2.x, t0i = a0.y + a2.y;
            float t1r = a0.x - a2.x, t1i = a0.y - a2.y;
            float t2r = a1.x + a3.x, t2i = a1.y + a3.y;
            float t3r = a1.y - a3.y, t3i = a3.x - a1.x;   // -i*(a1-a3)
            float y1r = t1r + t3r, y1i = t1i + t3i;
            float y2r = t0r - t2r, y2i = t0i - t2i;
            float y3r = t1r - t3r, y3i = t1i - t3i;
            zd[u][SWZ(o,          wf)] = make_float2(t0r + t2r,           t0i + t2i);
            zd[u][SWZ(o + mm,     wf)] = make_float2(y1r * c1 - y1i * s1, y1r * s1 + y1i * c1);
            zd[u][SWZ(o + 2 * mm, wf)] = make_float2(y2r * c2 - y2i * s2, y2r * s2 + y2i * c2);
            zd[u][SWZ(o + 3 * mm, wf)] = make_float2(y3r * c3 - y3i * s3, y3r * s3 + y3i * c3);
        }
        __syncthreads();
        float2 (*tp)[1024] = zs; zs = zd; zd = tp;
    }
    // 5 swaps: result in zs (=zB), DENSE natural order; zd (=zA) is scratch

    // ---- untangle: each 128-thread half handles its own FFT ----
    {
        const int u  = tid >> 7;
        const int kk = tid & 127;
        for (int k = kk; k < NBINS; k += 128) {
            float2 Z  = zs[u][k];
            const int kr = (NFFT - k) & (NFFT - 1);
            float2 Zr = zs[u][kr];
            float x1r = Z.x + Zr.x, x1i = Z.y - Zr.y;
            float x2r = Z.y + Zr.y, x2i = Zr.x - Z.x;
            zd[u][k] = make_float2(0.25f * (x1r * x1r + x1i * x1i),
                                   0.25f * (x2r * x2r + x2i * x2i));
        }
    }
    __syncthreads();

    // ---- mel projection: half u, mel m; both frames of FFT u at once ----
    {
        const int u = tid >> 7;
        const int m = tid & 127;
        const int fa = 4 * g + 2 * u;
        float acc0 = 0.f, acc1 = 0.f;
        if (usePacked) {
            const int k0 = kmin[m], L = klen[m];
            const float* w = wv + m * MAXW;
            for (int j = 0; j < L; ++j) {
                float2 pk = zd[u][k0 + j];
                float ww = w[j];
                acc0 += pk.x * ww; acc1 += pk.y * ww;
            }
        } else {
            for (int k = 0; k < NBINS; ++k) {
                float2 pk = zd[u][k];
                float ww = fb[k * NMELS + m];
                acc0 += pk.x * ww; acc1 += pk.y * ww;
            }
        }
        E[(size_t)fa * NMELS + m]       = acc0;
        E[(size_t)(fa + 1) * NMELS + m] = acc1;
    }
}

// ---------------------------------------------------------------------------
// PCEN phase 1: per-(b,chunk,m) affine offset B_c = s * sum_j a^{L-1-j} e_j.
// Full chunks: 16 independent loads in flight, 4 short FMA chains merged with
// a^4/a^8/a^12. Also snapshots E[:,0,:].
__global__ __launch_bounds__(256) void k_pcen_chunk(
    const float* __restrict__ E, float* __restrict__ Bws,
    float* __restrict__ E0ws, const float* __restrict__ p_ls)
{
    const int gid = blockIdx.x * blockDim.x + threadIdx.x;
    const int m = gid & (NMELS - 1);
    const int c = (gid >> 7) % NCHUNK;
    const int b = gid / (NMELS * NCHUNK);

    const float s = expf(p_ls[0]);
    const float a = 1.f - s;

    const int t0 = c * CL;
    const int L  = (t0 + CL <= NFRAMES) ? CL : (NFRAMES - t0);
    const float* col = E + (size_t)b * NFRAMES * NMELS + m;

    if (c == 0) E0ws[b * NMELS + m] = col[0];

    float Bacc;
    if (L == CL) {
        float e[CL];
        #pragma unroll
        for (int j = 0; j < CL; ++j)
            e[j] = col[(size_t)(t0 + j) * NMELS];
        float p0 = 0.f, p1 = 0.f, p2 = 0.f, p3 = 0.f;
        #pragma unroll
        for (int u = 0; u < 4; ++u) {
            p0 = a * p0 + s * e[u];
            p1 = a * p1 + s * e[4 + u];
            p2 = a * p2 + s * e[8 + u];
            p3 = a * p3 + s * e[12 + u];
        }
        const float a2 = a * a, a4 = a2 * a2, a8 = a4 * a4, a12 = a8 * a4;
        Bacc = a12 * p0 + a8 * p1 + a4 * p2 + p3;
    } else {
        Bacc = 0.f;
        for (int j = 0; j < L; ++j)
            Bacc = a * Bacc + s * col[(size_t)(t0 + j) * NMELS];
    }
    Bws[gid] = Bacc;
}

// ---------------------------------------------------------------------------
// PCEN phase 2 fused with layernorm. One block = (b, chunk-pair). Each half
// recomputes its chunk's EMA carry by scanning Bws (batched 8-wide loads),
// replays the chunk with pointwise PCEN into LDS, then 4 waves layernorm the
// 32 frames in place.
__global__ __launch_bounds__(256) void k_pcen_ln(
    float* __restrict__ E, const float* __restrict__ Bws,
    const float* __restrict__ E0ws,
    const float* __restrict__ p_ls, const float* __restrict__ p_la,
    const float* __restrict__ p_ld, const float* __restrict__ p_lr)
{
    __shared__ float sm[2 * CL][NMELS];   // 16 KB

    const int tid  = threadIdx.x;
    const int half = tid >> 7;
    const int m    = tid & 127;
    const int b    = blockIdx.x >> 5;     // 32 chunk-pairs per batch
    const int cp   = blockIdx.x & 31;
    const int c    = cp * 2 + half;

    const float s     = expf(p_ls[0]);
    const float alpha = expf(p_la[0]);
    const float delta = expf(p_ld[0]);
    const float r     = expf(p_lr[0]);
    const float dr    = __powf(delta, r);
    const float a     = 1.f - s;
    const float a2 = a * a, a4 = a2 * a2, a8 = a4 * a4;
    const float a16 = a8 * a8;            // a^CL (all scanned chunks full)

    if (c < NCHUNK) {
        // self-scan: carry entering chunk c, 8-wide batched loads for MLP
        float M = E0ws[b * NMELS + m];
        const float* Bcol = Bws + (size_t)b * NCHUNK * NMELS + m;
        int cc = 0;
        for (; cc + 8 <= c; cc += 8) {
            float b0 = Bcol[(size_t)(cc + 0) * NMELS];
            float b1 = Bcol[(size_t)(cc + 1) * NMELS];
            float b2 = Bcol[(size_t)(cc + 2) * NMELS];
            float b3 = Bcol[(size_t)(cc + 3) * NMELS];
            float b4 = Bcol[(size_t)(cc + 4) * NMELS];
            float b5 = Bcol[(size_t)(cc + 5) * NMELS];
            float b6 = Bcol[(size_t)(cc + 6) * NMELS];
            float b7 = Bcol[(size_t)(cc + 7) * NMELS];
            M = a16 * M + b0; M = a16 * M + b1; M = a16 * M + b2; M = a16 * M + b3;
            M = a16 * M + b4; M = a16 * M + b5; M = a16 * M + b6; M = a16 * M + b7;
        }
        for (; cc < c; ++cc)
            M = a16 * M + Bcol[(size_t)cc * NMELS];

        const int t0 = c * CL;
        const int L  = (t0 + CL <= NFRAMES) ? CL : (NFRAMES - t0);
        const float* col = E + ((size_t)b * NFRAMES + t0) * NMELS + m;
        for (int j = 0; j < L; ++j) {
            float e = col[(size_t)j * NMELS];
            M = a * M + s * e;
            float den = __powf(PCEN_EPS + M, alpha);
            sm[half * CL + j][m] = __powf(e / den + delta, r) - dr;
        }
    }
    __syncthreads();

    // layernorm: 4 waves cover the 32 staged frames
    const int wid  = tid >> 6;
    const int lane = tid & 63;
    for (int row = wid; row < 2 * CL; row += 4) {
        const int cc = cp * 2 + (row >> 4);
        if (cc >= NCHUNK) continue;
        const int j   = row & (CL - 1);
        const int tt0 = cc * CL;
        const int LL  = (tt0 + CL <= NFRAMES) ? CL : (NFRAMES - tt0);
        if (j >= LL) continue;
        float v0 = sm[row][lane], v1 = sm[row][lane + 64];
        float sum = v0 + v1;
        float sq  = v0 * v0 + v1 * v1;
        #pragma unroll
        for (int off = 32; off; off >>= 1) {
            sum += __shfl_xor(sum, off);
            sq  += __shfl_xor(sq,  off);
        }
        float mu  = sum * (1.f / 128.f);
        float var = sq * (1.f / 128.f) - mu * mu;
        float inv = rsqrtf(var + LN_EPS);
        float* p = E + ((size_t)b * NFRAMES + tt0 + j) * NMELS;
        p[lane]      = (v0 - mu) * inv;
        p[lane + 64] = (v1 - mu) * inv;
    }
}

// ---------------------------------------------------------------------------
// Fallback serial PCEN + LN (used only if workspace is too small).
__global__ __launch_bounds__(256) void k_pcen_serial(
    float* __restrict__ E,
    const float* __restrict__ p_ls, const float* __restrict__ p_la,
    const float* __restrict__ p_ld, const float* __restrict__ p_lr)
{
    const int gid = blockIdx.x * blockDim.x + threadIdx.x;
    const int b = gid >> 7;
    const int m = gid & 127;

    const float s     = expf(p_ls[0]);
    const float alpha = expf(p_la[0]);
    const float delta = expf(p_ld[0]);
    const float r     = expf(p_lr[0]);
    const float dr    = powf(delta, r);
    const float a     = 1.f - s;

    float* col = E + (size_t)b * NFRAMES * NMELS + m;
    float M = col[0];
    for (int t = 0; t < NFRAMES; ++t) {
        float e = col[(size_t)t * NMELS];
        M = a * M + s * e;
        float den = __powf(PCEN_EPS + M, alpha);
        float p   = __powf(e / den + delta, r) - dr;
        col[(size_t)t * NMELS] = p;
    }
}

__global__ __launch_bounds__(256) void k_ln(float* __restrict__ out) {
    const int wid  = threadIdx.x >> 6;
    const int lane = threadIdx.x & 63;
    const int row  = blockIdx.x * 4 + wid;
    float* p = out + (size_t)row * NMELS;
    float v0 = p[lane], v1 = p[lane + 64];
    float sum = v0 + v1;
    float sq  = v0 * v0 + v1 * v1;
    #pragma unroll
    for (int off = 32; off; off >>= 1) {
        sum += __shfl_xor(sum, off);
        sq  += __shfl_xor(sq,  off);
    }
    float mu  = sum * (1.f / 128.f);
    float var = sq * (1.f / 128.f) - mu * mu;
    float inv = rsqrtf(var + LN_EPS);
    p[lane]      = (v0 - mu) * inv;
    p[lane + 64] = (v1 - mu) * inv;
}

// ---------------------------------------------------------------------------
extern "C" void kernel_launch(void* const* d_in, const int* in_sizes, int n_in,
                              void* d_out, int out_size, void* d_ws, size_t ws_size,
                              hipStream_t stream) {
    const float* x   = (const float*)d_in[0];
    const float* fb  = (const float*)d_in[1];
    const float* lsp = (const float*)d_in[2];
    const float* lap = (const float*)d_in[3];
    const float* ldp = (const float*)d_in[4];
    const float* lrp = (const float*)d_in[5];
    float* out = (float*)d_out;

    // ws layout (floats): kmin[128] klen[128] wv[8192] win[1024] tw[512]
    //                     Bws[129024] E0ws[2048]
    const size_t packElems = 128 + 128 + 8192 + 1024 + 512;
    const size_t scanElems = (size_t)NB * NCHUNK * NMELS;   // 129024
    const size_t needPack  = packElems * 4;
    const size_t needScan  = (packElems + scanElems + (size_t)NB * NMELS) * 4;

    int usePacked = (ws_size >= needPack) ? 1 : 0;
    int useScan   = (ws_size >= needScan) ? 1 : 0;

    int*    kmin = (int*)d_ws;
    int*    klen = kmin + NMELS;
    float*  wv   = (float*)(klen + NMELS);
    float*  win  = wv + (size_t)NMELS * MAXW;
    float2* twg  = (float2*)(win + NFFT);
    float*  Bws  = (float*)(twg + 256);
    float*  E0ws = Bws + scanElems;

    if (usePacked)
        k_prep<<<NMELS + 5, 256, 0, stream>>>(fb, kmin, klen, wv, win, twg);

    k_melspec<<<NB * NFRAMES / 4, 256, 0, stream>>>(
        x, kmin, klen, wv, fb, win, twg, out, usePacked);

    if (useScan) {
        const int nThread = NB * NCHUNK * NMELS;                 // 129024
        k_pcen_chunk<<<nThread / 256, 256, 0, stream>>>(out, Bws, E0ws, lsp);
        k_pcen_ln<<<NB * 32, 256, 0, stream>>>(out, Bws, E0ws, lsp, lap, ldp, lrp);
    } else {
        k_pcen_serial<<<(NB * NMELS) / 256, 256, 0, stream>>>(out, lsp, lap, ldp, lrp);
        k_ln<<<(NB * NFRAMES) / 4, 256, 0, stream>>>(out);
    }
}

// Round 14
// 78.816 us; speedup vs baseline: 1.0747x; 1.0019x over previous
//
#include <hip/hip_runtime.h>
#include <math.h>

#define SRATE   32000
#define NFFT    1024
#define HOP     320
#define NBINS   513
#define NMELS   128
#define NFRAMES 1001
#define NB      16
#define TLEN    320000
#define PCEN_EPS 1e-6f
#define LN_EPS   1e-6f
#define MAXW     64   // max nonzero band width per mel column (measured ~27)

// ---- parallel-scan decomposition of the PCEN EMA ----
#define CL      16                    // chunk length (timesteps)
#define NCHUNK  63                    // ceil(1001/16)

// b64 bank swizzle: keeps every stage pattern at the 4-lane/bank-pair minimum.
__device__ __forceinline__ int SWZ(int i) {
    return i ^ (((i >> 6) & 3) << 2) ^ ((i >> 4) & 3);
}

__device__ __forceinline__ float2 cmul(float2 a, float2 b) {
    return make_float2(a.x * b.x - a.y * b.y, a.x * b.y + a.y * b.x);
}

// radix-4 DIF core: y_p = sum_q a_q * (-i)^(qp)
__device__ __forceinline__ void r4(float2 a0, float2 a1, float2 a2, float2 a3,
                                   float2& y0, float2& y1, float2& y2, float2& y3) {
    float t0r = a0.x + a2.x, t0i = a0.y + a2.y;
    float t1r = a0.x - a2.x, t1i = a0.y - a2.y;
    float t2r = a1.x + a3.x, t2i = a1.y + a3.y;
    float t3r = a1.y - a3.y, t3i = a3.x - a1.x;   // -i*(a1-a3)
    y0 = make_float2(t0r + t2r, t0i + t2i);
    y1 = make_float2(t1r + t3r, t1i + t3i);
    y2 = make_float2(t0r - t2r, t0i - t2i);
    y3 = make_float2(t1r - t3r, t1i - t3i);
}

// 16-point DFT, natural in/out: x[p] = sum_q x_q W16^(qp). Literal twiddles.
__device__ __forceinline__ void fft16(float2* x) {
    const float2 W1  = make_float2( 0.92387953f, -0.38268343f);
    const float2 W2  = make_float2( 0.70710678f, -0.70710678f);
    const float2 W3  = make_float2( 0.38268343f, -0.92387953f);
    const float2 W6  = make_float2(-0.70710678f, -0.70710678f);
    const float2 W9  = make_float2(-0.92387953f,  0.38268343f);
    float2 v[4][4];
    {
        float2 g0, g1, g2, g3;
        r4(x[0], x[4], x[8], x[12], g0, g1, g2, g3);
        v[0][0] = g0; v[1][0] = g1; v[2][0] = g2; v[3][0] = g3;
        r4(x[1], x[5], x[9], x[13], g0, g1, g2, g3);
        v[0][1] = g0; v[1][1] = cmul(g1, W1); v[2][1] = cmul(g2, W2); v[3][1] = cmul(g3, W3);
        r4(x[2], x[6], x[10], x[14], g0, g1, g2, g3);
        v[0][2] = g0; v[1][2] = cmul(g1, W2);
        v[2][2] = make_float2(g2.y, -g2.x);            // * W16^4 = -i
        v[3][2] = cmul(g3, W6);
        r4(x[3], x[7], x[11], x[15], g0, g1, g2, g3);
        v[0][3] = g0; v[1][3] = cmul(g1, W3); v[2][3] = cmul(g2, W6); v[3][3] = cmul(g3, W9);
    }
    #pragma unroll
    for (int p2 = 0; p2 < 4; ++p2) {
        float2 y0, y1, y2, y3;
        r4(v[p2][0], v[p2][1], v[p2][2], v[p2][3], y0, y1, y2, y3);
        x[p2] = y0; x[p2 + 4] = y1; x[p2 + 8] = y2; x[p2 + 12] = y3;
    }
}

// ---------------------------------------------------------------------------
// Parallel prep: one block per mel packs the filterbank band; 5 extra blocks
// build the window and float2 twiddle tables.
__global__ __launch_bounds__(256) void k_prep(
    const float* __restrict__ fb, int* __restrict__ kmin, int* __restrict__ klen,
    float* __restrict__ wv, float* __restrict__ win, float2* __restrict__ twg)
{
    const int blk = blockIdx.x;
    const int tid = threadIdx.x;
    if (blk < NMELS) {
        const int m = blk;
        __shared__ int smin[4], smax[4];
        int lmin = 1 << 30, lmax = -1;
        for (int k = tid; k < NBINS; k += 256) {
            if (fb[k * NMELS + m] > 0.f) {
                if (k < lmin) lmin = k;
                if (k > lmax) lmax = k;
            }
        }
        #pragma unroll
        for (int off = 32; off; off >>= 1) {
            int om = __shfl_xor(lmin, off); if (om < lmin) lmin = om;
            int ox = __shfl_xor(lmax, off); if (ox > lmax) lmax = ox;
        }
        if ((tid & 63) == 0) { smin[tid >> 6] = lmin; smax[tid >> 6] = lmax; }
        __syncthreads();
        int k0 = min(min(smin[0], smin[1]), min(smin[2], smin[3]));
        int k1 = max(max(smax[0], smax[1]), max(smax[2], smax[3]));
        int L  = (k1 < 0) ? 0 : min(k1 - k0 + 1, MAXW);
        if (tid == 0) { kmin[m] = (k1 < 0) ? 0 : k0; klen[m] = L; }
        if (tid < L) wv[m * MAXW + tid] = fb[(k0 + tid) * NMELS + m];
    } else {
        const int i = (blk - NMELS) * 256 + tid;   // 0..1279
        if (i < NFFT) {
            float sp = sinpif((float)i * (1.0f / (float)NFFT));
            win[i] = sp * sp;
        } else if (i < NFFT + 256) {
            int n = i - NFFT;
            float sn, cn;
            sincospif((float)n * (1.0f / 512.0f), &sn, &cn);
            twg[n] = make_float2(cn, -sn);
        }
    }
}

// ---------------------------------------------------------------------------
// Wave-autonomous mel-spectrogram: one WAVE = one two-for-one real FFT
// (2 frames); block = 4 waves = 8 frames. 1024 = 16*16*4 in-place DIF:
// 3 LDS round-trips, ZERO __syncthreads (all state wave-local).
// X[p1+16p2+256k3] lives at slot 64p1+4p2+k3 (in-place DIF recursion).
__global__ __launch_bounds__(256, 4) void k_melspec(
    const float* __restrict__ x,
    const int*   __restrict__ kmin,
    const int*   __restrict__ klen,
    const float* __restrict__ wv,
    const float* __restrict__ fb,     // dense fallback
    const float* __restrict__ win_g,
    const float2* __restrict__ twg,
    float* __restrict__ E,
    int usePacked)
{
    __shared__ float2 z[4][1024];            // 32 KB, slab w owned by wave w
    __shared__ float2 tws_sh[64];            // W_1024^n, n<64 (wave-redundant)
    __shared__ unsigned short prt[513];      // slot of X[k] (wave-redundant)

    const int tid  = threadIdx.x;
    const int w    = tid >> 6;               // wave id = FFT id
    const int lane = tid & 63;
    const int g    = blockIdx.x;             // frames 8g .. 8g+7
    float2* T = z[w];

    // ---- per-wave tables (every wave writes the full table -> no barrier) ----
    if (usePacked) {
        tws_sh[lane] = twg[lane];
    } else {
        float sn, cn;
        sincospif((float)lane * (1.0f / 512.0f), &sn, &cn);
        tws_sh[lane] = make_float2(cn, -sn);
    }
    for (int k = lane; k <= 512; k += 64) {
        const int sl = 64 * (k & 15) + 4 * ((k >> 4) & 15) + (k >> 8);
        prt[k] = (unsigned short)SWZ(sl);
    }

    // ---- stage 2 frames into T (wave-local) ----
    {
        const int fa = 8 * g + 2 * w, fbf = fa + 1;
        const int ba = fa / NFRAMES,  ta = fa  - ba * NFRAMES;
        const int bb = fbf / NFRAMES, tb = fbf - bb * NFRAMES;
        const float* xa = x + (size_t)ba * TLEN;
        const float* xb = x + (size_t)bb * TLEN;
        const int basea = ta * HOP - (NFFT / 2);
        const int baseb = tb * HOP - (NFFT / 2);
        const bool safe = usePacked &&
                          basea >= 0 && baseb >= 0 &&
                          (basea + NFFT - 1 < TLEN) && (baseb + NFFT - 1 < TLEN);
        if (safe) {
            #pragma unroll
            for (int q = 0; q < 4; ++q) {
                const int i0 = 4 * lane + 256 * q;
                float4 v0 = *(const float4*)(xa + basea + i0);
                float4 v1 = *(const float4*)(xb + baseb + i0);
                float4 ww = *(const float4*)(win_g + i0);
                T[SWZ(i0 + 0)] = make_float2(v0.x * ww.x, v1.x * ww.x);
                T[SWZ(i0 + 1)] = make_float2(v0.y * ww.y, v1.y * ww.y);
                T[SWZ(i0 + 2)] = make_float2(v0.z * ww.z, v1.z * ww.z);
                T[SWZ(i0 + 3)] = make_float2(v0.w * ww.w, v1.w * ww.w);
            }
        } else {
            for (int i = lane; i < NFFT; i += 64) {
                int j0 = basea + i;
                j0 = (j0 < 0) ? -j0 : ((j0 >= TLEN) ? (2 * TLEN - 2 - j0) : j0);
                int j1 = baseb + i;
                j1 = (j1 < 0) ? -j1 : ((j1 >= TLEN) ? (2 * TLEN - 2 - j1) : j1);
                float ww;
                if (usePacked) ww = win_g[i];
                else { float sp = sinpif((float)i * (1.0f / (float)NFFT)); ww = sp * sp; }
                T[SWZ(i)] = make_float2(xa[j0] * ww, xb[j1] * ww);
            }
        }
    }

    float2 xr[16];

    // ---- S1: radix-16, stride 64; butterfly j = lane; twiddle W_1024^(j*p) ----
    {
        #pragma unroll
        for (int q = 0; q < 16; ++q) xr[q] = T[SWZ(lane + 64 * q)];
        fft16(xr);
        const float2 w1 = tws_sh[lane];
        float2 wp = w1;
        T[SWZ(lane)] = xr[0];
        #pragma unroll
        for (int p = 1; p < 16; ++p) {
            T[SWZ(lane + 64 * p)] = cmul(xr[p], wp);
            wp = cmul(wp, w1);
        }
    }

    // ---- S2: radix-16 within 64-blocks, stride 4; twiddle W_64^(j*p) ----
    {
        const int p1 = lane >> 2, jj = lane & 3;
        const int base = 64 * p1 + jj;
        #pragma unroll
        for (int q = 0; q < 16; ++q) xr[q] = T[SWZ(base + 4 * q)];
        fft16(xr);
        const float2 w1 = tws_sh[16 * jj];
        float2 wp = w1;
        T[SWZ(base)] = xr[0];
        #pragma unroll
        for (int p = 1; p < 16; ++p) {
            T[SWZ(base + 4 * p)] = cmul(xr[p], wp);
            wp = cmul(wp, w1);
        }
    }

    // ---- S3: radix-4 within 4-blocks, no twiddle ----
    #pragma unroll
    for (int h = 0; h < 4; ++h) {
        const int b4 = 4 * (lane + 64 * h);
        float2 a0 = T[SWZ(b4)], a1 = T[SWZ(b4 + 1)], a2 = T[SWZ(b4 + 2)], a3 = T[SWZ(b4 + 3)];
        float2 y0, y1, y2, y3;
        r4(a0, a1, a2, a3, y0, y1, y2, y3);
        T[SWZ(b4)] = y0; T[SWZ(b4 + 1)] = y1; T[SWZ(b4 + 2)] = y2; T[SWZ(b4 + 3)] = y3;
    }

    // ---- untangle in place (write set {prt[k],k<=512} disjoint from mirror
    //      reads, all wave-local) ----
    for (int k = lane; k <= 512; k += 64) {
        const int sk = prt[k];
        const int kr = (NFFT - k) & (NFFT - 1);
        const int slr = SWZ(64 * (kr & 15) + 4 * ((kr >> 4) & 15) + (kr >> 8));
        float2 Z  = T[sk];
        float2 Zr = T[slr];
        float x1r = Z.x + Zr.x, x1i = Z.y - Zr.y;
        float x2r = Z.y + Zr.y, x2i = Zr.x - Z.x;
        T[sk] = make_float2(0.25f * (x1r * x1r + x1i * x1i),
                            0.25f * (x2r * x2r + x2i * x2i));
    }

    // ---- mel projection: lane handles mels {lane, lane+64} for its FFT ----
    {
        const int f0 = 8 * g + 2 * w;
        #pragma unroll
        for (int h = 0; h < 2; ++h) {
            const int m = lane + 64 * h;
            float acc0 = 0.f, acc1 = 0.f;
            if (usePacked) {
                const int k0 = kmin[m], L = klen[m];
                const float* wz = wv + m * MAXW;
                for (int j = 0; j < L; ++j) {
                    float2 pk = T[prt[k0 + j]];
                    float ww = wz[j];
                    acc0 += pk.x * ww; acc1 += pk.y * ww;
                }
            } else {
                for (int k = 0; k < NBINS; ++k) {
                    float2 pk = T[prt[k]];
                    float ww = fb[k * NMELS + m];
                    acc0 += pk.x * ww; acc1 += pk.y * ww;
                }
            }
            E[(size_t)f0 * NMELS + m]       = acc0;
            E[(size_t)(f0 + 1) * NMELS + m] = acc1;
        }
    }
}

// ---------------------------------------------------------------------------
// PCEN phase 1: per-(b,chunk,m) affine offset B_c = s * sum_j a^{L-1-j} e_j.
// Full chunks: 16 independent loads in flight, 4 short FMA chains merged with
// a^4/a^8/a^12. Also snapshots E[:,0,:].
__global__ __launch_bounds__(256) void k_pcen_chunk(
    const float* __restrict__ E, float* __restrict__ Bws,
    float* __restrict__ E0ws, const float* __restrict__ p_ls)
{
    const int gid = blockIdx.x * blockDim.x + threadIdx.x;
    const int m = gid & (NMELS - 1);
    const int c = (gid >> 7) % NCHUNK;
    const int b = gid / (NMELS * NCHUNK);

    const float s = expf(p_ls[0]);
    const float a = 1.f - s;

    const int t0 = c * CL;
    const int L  = (t0 + CL <= NFRAMES) ? CL : (NFRAMES - t0);
    const float* col = E + (size_t)b * NFRAMES * NMELS + m;

    if (c == 0) E0ws[b * NMELS + m] = col[0];

    float Bacc;
    if (L == CL) {
        float e[CL];
        #pragma unroll
        for (int j = 0; j < CL; ++j)
            e[j] = col[(size_t)(t0 + j) * NMELS];
        float p0 = 0.f, p1 = 0.f, p2 = 0.f, p3 = 0.f;
        #pragma unroll
        for (int u = 0; u < 4; ++u) {
            p0 = a * p0 + s * e[u];
            p1 = a * p1 + s * e[4 + u];
            p2 = a * p2 + s * e[8 + u];
            p3 = a * p3 + s * e[12 + u];
        }
        const float a2 = a * a, a4 = a2 * a2, a8 = a4 * a4, a12 = a8 * a4;
        Bacc = a12 * p0 + a8 * p1 + a4 * p2 + p3;
    } else {
        Bacc = 0.f;
        for (int j = 0; j < L; ++j)
            Bacc = a * Bacc + s * col[(size_t)(t0 + j) * NMELS];
    }
    Bws[gid] = Bacc;
}

// ---------------------------------------------------------------------------
// PCEN phase 2 fused with layernorm. One block = (b, chunk-pair). Each half
// recomputes its chunk's EMA carry by scanning Bws (batched 8-wide loads),
// replays the chunk with pointwise PCEN into LDS, then 4 waves layernorm the
// 32 frames in place.
__global__ __launch_bounds__(256) void k_pcen_ln(
    float* __restrict__ E, const float* __restrict__ Bws,
    const float* __restrict__ E0ws,
    const float* __restrict__ p_ls, const float* __restrict__ p_la,
    const float* __restrict__ p_ld, const float* __restrict__ p_lr)
{
    __shared__ float sm[2 * CL][NMELS];   // 16 KB

    const int tid  = threadIdx.x;
    const int half = tid >> 7;
    const int m    = tid & 127;
    const int b    = blockIdx.x >> 5;     // 32 chunk-pairs per batch
    const int cp   = blockIdx.x & 31;
    const int c    = cp * 2 + half;

    const float s     = expf(p_ls[0]);
    const float alpha = expf(p_la[0]);
    const float delta = expf(p_ld[0]);
    const float r     = expf(p_lr[0]);
    const float dr    = __powf(delta, r);
    const float a     = 1.f - s;
    const float a2 = a * a, a4 = a2 * a2, a8 = a4 * a4;
    const float a16 = a8 * a8;            // a^CL (all scanned chunks full)

    if (c < NCHUNK) {
        // self-scan: carry entering chunk c, 8-wide batched loads for MLP
        float M = E0ws[b * NMELS + m];
        const float* Bcol = Bws + (size_t)b * NCHUNK * NMELS + m;
        int cc = 0;
        for (; cc + 8 <= c; cc += 8) {
            float b0 = Bcol[(size_t)(cc + 0) * NMELS];
            float b1 = Bcol[(size_t)(cc + 1) * NMELS];
            float b2 = Bcol[(size_t)(cc + 2) * NMELS];
            float b3 = Bcol[(size_t)(cc + 3) * NMELS];
            float b4 = Bcol[(size_t)(cc + 4) * NMELS];
            float b5 = Bcol[(size_t)(cc + 5) * NMELS];
            float b6 = Bcol[(size_t)(cc + 6) * NMELS];
            float b7 = Bcol[(size_t)(cc + 7) * NMELS];
            M = a16 * M + b0; M = a16 * M + b1; M = a16 * M + b2; M = a16 * M + b3;
            M = a16 * M + b4; M = a16 * M + b5; M = a16 * M + b6; M = a16 * M + b7;
        }
        for (; cc < c; ++cc)
            M = a16 * M + Bcol[(size_t)cc * NMELS];

        const int t0 = c * CL;
        const int L  = (t0 + CL <= NFRAMES) ? CL : (NFRAMES - t0);
        const float* col = E + ((size_t)b * NFRAMES + t0) * NMELS + m;
        for (int j = 0; j < L; ++j) {
            float e = col[(size_t)j * NMELS];
            M = a * M + s * e;
            float den = __powf(PCEN_EPS + M, alpha);
            sm[half * CL + j][m] = __powf(e / den + delta, r) - dr;
        }
    }
    __syncthreads();

    // layernorm: 4 waves cover the 32 staged frames
    const int wid  = tid >> 6;
    const int lane = tid & 63;
    for (int row = wid; row < 2 * CL; row += 4) {
        const int cc = cp * 2 + (row >> 4);
        if (cc >= NCHUNK) continue;
        const int j   = row & (CL - 1);
        const int tt0 = cc * CL;
        const int LL  = (tt0 + CL <= NFRAMES) ? CL : (NFRAMES - tt0);
        if (j >= LL) continue;
        float v0 = sm[row][lane], v1 = sm[row][lane + 64];
        float sum = v0 + v1;
        float sq  = v0 * v0 + v1 * v1;
        #pragma unroll
        for (int off = 32; off; off >>= 1) {
            sum += __shfl_xor(sum, off);
            sq  += __shfl_xor(sq,  off);
        }
        float mu  = sum * (1.f / 128.f);
        float var = sq * (1.f / 128.f) - mu * mu;
        float inv = rsqrtf(var + LN_EPS);
        float* p = E + ((size_t)b * NFRAMES + tt0 + j) * NMELS;
        p[lane]      = (v0 - mu) * inv;
        p[lane + 64] = (v1 - mu) * inv;
    }
}

// ---------------------------------------------------------------------------
// Fallback serial PCEN + LN (used only if workspace is too small).
__global__ __launch_bounds__(256) void k_pcen_serial(
    float* __restrict__ E,
    const float* __restrict__ p_ls, const float* __restrict__ p_la,
    const float* __restrict__ p_ld, const float* __restrict__ p_lr)
{
    const int gid = blockIdx.x * blockDim.x + threadIdx.x;
    const int b = gid >> 7;
    const int m = gid & 127;

    const float s     = expf(p_ls[0]);
    const float alpha = expf(p_la[0]);
    const float delta = expf(p_ld[0]);
    const float r     = expf(p_lr[0]);
    const float dr    = powf(delta, r);
    const float a     = 1.f - s;

    float* col = E + (size_t)b * NFRAMES * NMELS + m;
    float M = col[0];
    for (int t = 0; t < NFRAMES; ++t) {
        float e = col[(size_t)t * NMELS];
        M = a * M + s * e;
        float den = __powf(PCEN_EPS + M, alpha);
        float p   = __powf(e / den + delta, r) - dr;
        col[(size_t)t * NMELS] = p;
    }
}

__global__ __launch_bounds__(256) void k_ln(float* __restrict__ out) {
    const int wid  = threadIdx.x >> 6;
    const int lane = threadIdx.x & 63;
    const int row  = blockIdx.x * 4 + wid;
    float* p = out + (size_t)row * NMELS;
    float v0 = p[lane], v1 = p[lane + 64];
    float sum = v0 + v1;
    float sq  = v0 * v0 + v1 * v1;
    #pragma unroll
    for (int off = 32; off; off >>= 1) {
        sum += __shfl_xor(sum, off);
        sq  += __shfl_xor(sq,  off);
    }
    float mu  = sum * (1.f / 128.f);
    float var = sq * (1.f / 128.f) - mu * mu;
    float inv = rsqrtf(var + LN_EPS);
    p[lane]      = (v0 - mu) * inv;
    p[lane + 64] = (v1 - mu) * inv;
}

// ---------------------------------------------------------------------------
extern "C" void kernel_launch(void* const* d_in, const int* in_sizes, int n_in,
                              void* d_out, int out_size, void* d_ws, size_t ws_size,
                              hipStream_t stream) {
    const float* x   = (const float*)d_in[0];
    const float* fb  = (const float*)d_in[1];
    const float* lsp = (const float*)d_in[2];
    const float* lap = (const float*)d_in[3];
    const float* ldp = (const float*)d_in[4];
    const float* lrp = (const float*)d_in[5];
    float* out = (float*)d_out;

    // ws layout (floats): kmin[128] klen[128] wv[8192] win[1024] tw[512]
    //                     Bws[129024] E0ws[2048]
    const size_t packElems = 128 + 128 + 8192 + 1024 + 512;
    const size_t scanElems = (size_t)NB * NCHUNK * NMELS;   // 129024
    const size_t needPack  = packElems * 4;
    const size_t needScan  = (packElems + scanElems + (size_t)NB * NMELS) * 4;

    int usePacked = (ws_size >= needPack) ? 1 : 0;
    int useScan   = (ws_size >= needScan) ? 1 : 0;

    int*    kmin = (int*)d_ws;
    int*    klen = kmin + NMELS;
    float*  wv   = (float*)(klen + NMELS);
    float*  win  = wv + (size_t)NMELS * MAXW;
    float2* twg  = (float2*)(win + NFFT);
    float*  Bws  = (float*)(twg + 256);
    float*  E0ws = Bws + scanElems;

    if (usePacked)
        k_prep<<<NMELS + 5, 256, 0, stream>>>(fb, kmin, klen, wv, win, twg);

    k_melspec<<<NB * NFRAMES / 8, 256, 0, stream>>>(
        x, kmin, klen, wv, fb, win, twg, out, usePacked);

    if (useScan) {
        const int nThread = NB * NCHUNK * NMELS;                 // 129024
        k_pcen_chunk<<<nThread / 256, 256, 0, stream>>>(out, Bws, E0ws, lsp);
        k_pcen_ln<<<NB * 32, 256, 0, stream>>>(out, Bws, E0ws, lsp, lap, ldp, lrp);
    } else {
        k_pcen_serial<<<(NB * NMELS) / 256, 256, 0, stream>>>(out, lsp, lap, ldp, lrp);
        k_ln<<<(NB * NFRAMES) / 4, 256, 0, stream>>>(out);
    }
}